// Round 1
// baseline (133.273 us; speedup 1.0000x reference)
//
#include <hip/hip_runtime.h>
#include <hip/hip_bf16.h>

// Problem constants
#define BATCH  16384
#define INF    256
#define GATES  1023
#define NPAD   1024
#define OUTF   128
#define LEAVES 1024

typedef unsigned short ushortT;
typedef short bf16x8 __attribute__((ext_vector_type(8)));
typedef float f32x4 __attribute__((ext_vector_type(4)));

__device__ inline float bf2f(ushortT u) {
    union { unsigned int i; float f; } v;
    v.i = ((unsigned int)u) << 16;
    return v.f;
}
__device__ inline ushortT f2bf(float f) {
    union { float f; unsigned int i; } v;
    v.f = f;
    unsigned int x = v.i;
    unsigned int r = (x + 0x7FFFu + ((x >> 16) & 1u)) >> 16;  // RNE
    return (ushortT)r;
}

// async global->LDS, 16B per lane; ldsptr must be wave-uniform base,
// HW writes base + lane*16 (guide §5 caveat).
__device__ inline void gl2lds16(const void* gptr, void* ldsptr) {
    __builtin_amdgcn_global_load_lds(
        (const __attribute__((address_space(1))) void*)gptr,
        (__attribute__((address_space(3))) void*)ldsptr, 16, 0, 0);
}

// ---------------- converts ----------------
__global__ void k_convert_f32_bf16(const float* __restrict__ in,
                                   ushortT* __restrict__ out, int n8) {
    int i = blockIdx.x * blockDim.x + threadIdx.x;
    if (i >= n8) return;
    const float4* p = (const float4*)in + (size_t)i * 2;
    float4 a = p[0], b = p[1];
    ushortT o[8] = {f2bf(a.x), f2bf(a.y), f2bf(a.z), f2bf(a.w),
                    f2bf(b.x), f2bf(b.y), f2bf(b.z), f2bf(b.w)};
    *(bf16x8*)(out + (size_t)i * 8) = *(bf16x8*)o;
}

// gw (256 x 1023) -> gwT (1024 x 256) bf16, padded row 1023 = 0; gb -> gbp (1024)
__global__ void k_prep_w(const float* __restrict__ gw, const float* __restrict__ gb,
                         ushortT* __restrict__ gwT, float* __restrict__ gbp) {
    int id = blockIdx.x * 256 + threadIdx.x;  // 262144 threads
    int n = id >> 8, k = id & 255;
    float v = (n < GATES) ? gw[k * GATES + n] : 0.f;
    gwT[n * 256 + k] = f2bf(v);
    if (id < NPAD) gbp[id] = (id < GATES) ? gb[id] : 0.f;
}

// ---------------- GEMM (m97 structure): C[M,N] = A[M,K] * B^T[N,K] ----------------
// 256 threads = 4 waves in 2x2; wave tile (BM/2 x BN/2); 16x16x32 bf16 MFMA.
template <int BM, int BN, int K, int LDA, int LDB, int LDC, bool SIG>
__global__ __launch_bounds__(256) void gemm_bt(const ushortT* __restrict__ A,
                                               const ushortT* __restrict__ B,
                                               const float* __restrict__ bias,
                                               void* __restrict__ Cv) {
    constexpr int MT = BM / 32, NT = BN / 32;
    constexpr int RA = BM / 64, RB = BN / 64;  // staging rounds per wave
    __shared__ ushortT sA[BM * 32];
    __shared__ ushortT sB[BN * 32];

    const int tid = threadIdx.x;
    const int wave = tid >> 6, lane = tid & 63;
    const int quad = lane >> 4, l15 = lane & 15;
    const int wr = wave >> 1, wc = wave & 1;
    const int m_wave = wr * (BM / 2), n_wave = wc * (BN / 2);
    const int bm = blockIdx.y * BM, bn = blockIdx.x * BN;

    const int r_in = lane >> 2;            // row within 16-row issue
    const int c_in = (lane & 3) * 8;       // elem col within 32-elem row

    f32x4 acc[MT][NT] = {};

    const ushortT* Abase = A + (size_t)bm * LDA;
    const ushortT* Bbase = B + (size_t)bn * LDB;

    for (int k0 = 0; k0 < K; k0 += 32) {
#pragma unroll
        for (int r = 0; r < RA; ++r) {
            int e = wave * RA + r;
            gl2lds16(Abase + (size_t)(e * 16 + r_in) * LDA + k0 + c_in, sA + e * 512);
        }
#pragma unroll
        for (int r = 0; r < RB; ++r) {
            int e = wave * RB + r;
            gl2lds16(Bbase + (size_t)(e * 16 + r_in) * LDB + k0 + c_in, sB + e * 512);
        }
        __syncthreads();

        bf16x8 af[MT], bfr[NT];
#pragma unroll
        for (int i = 0; i < MT; ++i)
            af[i] = *(const bf16x8*)(sA + (m_wave + i * 16 + l15) * 32 + quad * 8);
#pragma unroll
        for (int j = 0; j < NT; ++j)
            bfr[j] = *(const bf16x8*)(sB + (n_wave + j * 16 + l15) * 32 + quad * 8);
#pragma unroll
        for (int i = 0; i < MT; ++i)
#pragma unroll
            for (int j = 0; j < NT; ++j)
                acc[i][j] = __builtin_amdgcn_mfma_f32_16x16x32_bf16(af[i], bfr[j],
                                                                    acc[i][j], 0, 0, 0);
        __syncthreads();
    }

    // Epilogue. C/D mapping: col = lane&15, row = quad*4 + reg (guide §3, m89-verified)
    if constexpr (SIG) {
        ushortT* C = (ushortT*)Cv;
#pragma unroll
        for (int i = 0; i < MT; ++i) {
            int gm = bm + m_wave + i * 16 + quad * 4;
#pragma unroll
            for (int j = 0; j < NT; ++j) {
                int gn = bn + n_wave + j * 16 + l15;
                float bs = bias[gn];
#pragma unroll
                for (int r = 0; r < 4; ++r) {
                    float logit = acc[i][j][r] + bs;
                    float g = 1.f / (1.f + __expf(-logit));
                    C[(size_t)(gm + r) * LDC + gn] = f2bf(g);
                }
            }
        }
    } else {
        float* C = (float*)Cv;
#pragma unroll
        for (int i = 0; i < MT; ++i) {
            int gm = bm + m_wave + i * 16 + quad * 4;
#pragma unroll
            for (int j = 0; j < NT; ++j) {
                int gn = bn + n_wave + j * 16 + l15;
#pragma unroll
                for (int r = 0; r < 4; ++r)
                    C[(size_t)(gm + r) * LDC + gn] = acc[i][j][r];
            }
        }
    }
}

// ---------------- tree: gatings (bf16, row-major 1024) -> leaf densities (bf16) --------
// one wave per batch row; lane owns 16 consecutive leaves (6-bit prefix = lane)
__global__ __launch_bounds__(256) void k_tree(const ushortT* __restrict__ gat,
                                              ushortT* __restrict__ leaf) {
    const int wave = threadIdx.x >> 6, lane = threadIdx.x & 63;
    const int row = blockIdx.x * 4 + wave;
    const ushortT* gr = gat + (size_t)row * NPAD;

    // prefix over depths 0..5
    float P = 1.f;
#pragma unroll
    for (int d = 0; d < 6; ++d) {
        int idx = (1 << d) - 1 + (lane >> (6 - d));
        float g = bf2f(gr[idx]);
        int bit = (lane >> (5 - d)) & 1;
        P *= bit ? (1.f - g) : g;
    }
    // register doubling over depths 6..9
    float v[16];
    v[0] = P;
#pragma unroll
    for (int d = 0; d < 4; ++d) {
        const int cnt = 1 << d;
        const int base = (1 << (d + 6)) - 1 + (lane << d);
#pragma unroll
        for (int t = 7; t >= 0; --t) {
            if (t < cnt) {
                float g = bf2f(gr[base + t]);
                float pv = v[t];
                float a = pv * g;
                v[2 * t] = a;
                v[2 * t + 1] = pv - a;  // pv*(1-g)
            }
        }
    }
    ushortT o[16];
#pragma unroll
    for (int t = 0; t < 16; ++t) o[t] = f2bf(v[t]);
    ushortT* dst = leaf + (size_t)row * LEAVES + lane * 16;
    *(bf16x8*)(dst) = *(bf16x8*)(o);
    *(bf16x8*)(dst + 8) = *(bf16x8*)(o + 8);
}

// ---------------- launch ----------------
extern "C" void kernel_launch(void* const* d_in, const int* in_sizes, int n_in,
                              void* d_out, int out_size, void* d_ws, size_t ws_size,
                              hipStream_t stream) {
    const float* x  = (const float*)d_in[0];   // 16384 x 256
    const float* gw = (const float*)d_in[1];   // 256 x 1023
    const float* gb = (const float*)d_in[2];   // 1023
    const float* z  = (const float*)d_in[3];   // 128 x 1024
    float* out = (float*)d_out;                // 16384 x 128

    char* ws = (char*)d_ws;
    ushortT* xh   = (ushortT*)(ws + 0);         //  8,388,608 B
    ushortT* gwT  = (ushortT*)(ws + 8388608);   //    524,288 B
    ushortT* zh   = (ushortT*)(ws + 8912896);   //    262,144 B
    float*   gbp  = (float*)  (ws + 9175040);   //      4,096 B
    ushortT* gat  = (ushortT*)(ws + 9179136);   // 33,554,432 B
    ushortT* leaf = (ushortT*)(ws + 42733568);  // 33,554,432 B  (total ~76.3 MB)

    k_convert_f32_bf16<<<2048, 256, 0, stream>>>(x, xh, 524288);
    k_convert_f32_bf16<<<64, 256, 0, stream>>>(z, zh, 16384);
    k_prep_w<<<1024, 256, 0, stream>>>(gw, gb, gwT, gbp);

    // GEMM1: gatings = sigmoid(x @ gw + gb), M=16384 N=1024 K=256
    gemm_bt<128, 128, 256, 256, 256, 1024, true>
        <<<dim3(8, 128), 256, 0, stream>>>(xh, gwT, gbp, gat);

    k_tree<<<4096, 256, 0, stream>>>(gat, leaf);

    // GEMM2: out = leaf @ z^T, M=16384 N=128 K=1024 (z already N x K)
    gemm_bt<128, 64, 1024, 1024, 1024, 128, false>
        <<<dim3(2, 128), 256, 0, stream>>>(leaf, zh, nullptr, out);
}